// Round 3
// baseline (1204.640 us; speedup 1.0000x reference)
//
#include <hip/hip_runtime.h>
#include <hip/hip_bf16.h>
#include <math.h>

// Problem constants
#define BB 256
#define T2C 1026
#define TP1 1025
#define SS 1024
#define HH 32
#define EVN 32
#define VOCAB 35
#define NH7 224            // 7*H
#define NROWS 262400       // B*Tp1
#define NROWS_USED 262144  // B*S
#define EPSF 2.220446049250313e-16f

// ws layout in floats:
//  [0, NROWS*128)          ccdo rows: per (b,t): c[32], cbar[32], delta[32], o[32]
//  [H_F, +NROWS*32)        h rows
//  [EMBW_F, +35*224)       EmbW (x@W[:32,:] + b per vocab word)
//  [ACC_F, +1024)          per-b scalars: numer[256] | den[256] | loglam_b[256] | nev_b[256]
//  [W2T_F, +224*32)        W2 transposed: W2T[col][k] = W[(32+k)*224 + col]
#define H_F    ((size_t)NROWS * 128)               // 33,587,200
#define EMBW_F (H_F + (size_t)NROWS * HH)          // 41,984,000
#define ACC_F  (EMBW_F + (size_t)VOCAB * NH7)      // 41,991,840
#define W2T_F  (ACC_F + 1024)                      // 41,992,864

__device__ __forceinline__ float softplusf(float x) {
    return fmaxf(x, 0.f) + log1pf(expf(-fabsf(x)));
}
__device__ __forceinline__ float sigmoidf_(float x) {
    return 1.f / (1.f + expf(-x));
}

// ---------------- K0: EmbW precompute + W2 transpose ----------------
__global__ __launch_bounds__(256) void k0_embw(const float* __restrict__ Emb,
                                               const float* __restrict__ W,
                                               const float* __restrict__ bias,
                                               float* __restrict__ ws) {
    int j = threadIdx.x;
    __shared__ float embs[VOCAB * HH];
    for (int idx = j; idx < VOCAB * HH; idx += 256) embs[idx] = Emb[idx];
    // W2T[c][k] = W[(32+k)*224 + c]
    for (int idx = j; idx < NH7 * HH; idx += 256) {
        int c = idx >> 5, k = idx & 31;
        ws[W2T_F + idx] = W[(HH + k) * NH7 + c];
    }
    __syncthreads();
    if (j < NH7) {
        for (int v = 0; v < VOCAB; v++) {
            float s = bias[j];
#pragma unroll
            for (int k = 0; k < HH; k++) s = fmaf(embs[v * HH + k], W[k * NH7 + j], s);
            ws[EMBW_F + v * NH7 + j] = s;
        }
    }
}

// ---------------- K1: sequential CTLSTM scan — ONE WAVE per batch, no barriers ----------------
// Lane l owns columns {l, l+64, l+128, l+192(if l<32)}:
//   l<32 : gates i(c0), z(c1), ib(c2), d(c3) of output column l
//   l>=32: gates f(c0), o(c1), fb(c2)        of output column l-32
__global__ __launch_bounds__(64) void k1_recur(const int* __restrict__ event,
                                               const float* __restrict__ dtime,
                                               float* ws) {
    const int b = blockIdx.x;
    const int l = threadIdx.x;  // 0..63
    __shared__ float embw[VOCAB * NH7];
    __shared__ float dt_s[TP1];
    __shared__ int ev_s[TP1 + 1];
    __shared__ __align__(16) float h_s[HH];

    for (int idx = l; idx < VOCAB * NH7; idx += 64) embw[idx] = ws[EMBW_F + idx];
    for (int idx = l; idx < TP1 + 1; idx += 64) {
        ev_s[idx] = (idx < TP1) ? event[b * T2C + idx] : 0;
        if (idx < TP1) dt_s[idx] = dtime[b * T2C + idx + 1];
    }
    if (l < HH) h_s[l] = 0.f;

    const int c0 = l, c1 = l + 64, c2 = l + 128, c3 = l + 192;  // c3 valid only l<32
    const bool lo = (l < HH);
    // W2 columns into registers (vectorized from W2T staged by k0)
    float wk0[HH], wk1[HH], wk2[HH], wk3[HH];
    {
        const float4* w2t = (const float4*)(ws + W2T_F);
#pragma unroll
        for (int q = 0; q < 8; q++) {
            float4 a = w2t[c0 * 8 + q];
            wk0[4 * q] = a.x; wk0[4 * q + 1] = a.y; wk0[4 * q + 2] = a.z; wk0[4 * q + 3] = a.w;
            float4 bq = w2t[c1 * 8 + q];
            wk1[4 * q] = bq.x; wk1[4 * q + 1] = bq.y; wk1[4 * q + 2] = bq.z; wk1[4 * q + 3] = bq.w;
            float4 cq = w2t[c2 * 8 + q];
            wk2[4 * q] = cq.x; wk2[4 * q + 1] = cq.y; wk2[4 * q + 2] = cq.z; wk2[4 * q + 3] = cq.w;
            float4 dq = lo ? w2t[c3 * 8 + q] : make_float4(0.f, 0.f, 0.f, 0.f);
            wk3[4 * q] = dq.x; wk3[4 * q + 1] = dq.y; wk3[4 * q + 2] = dq.z; wk3[4 * q + 3] = dq.w;
        }
    }
    float c_m = 0.f, cb_m = 0.f;
    float* ccdo_base = ws + (size_t)b * TP1 * 128;
    float* h_base = ws + H_F + (size_t)b * TP1 * HH;
    __syncthreads();  // single wave: cheap; orders init loads

    int ev = ev_s[0];
    for (int t = 0; t < TP1; t++) {
        // EmbW contributions for current event (LDS; latency hides under GEMV issue)
        const float* eb = embw + ev * NH7;
        float eb0 = eb[c0], eb1 = eb[c1], eb2 = eb[c2], eb3 = lo ? eb[c3] : 0.f;
        ev = ev_s[t + 1];  // prefetch next event index
        float dt = dt_s[t];

        // h broadcast read (written by lanes<32 at end of previous step; same-wave DS order)
        const float4* h4 = (const float4*)h_s;
        float acc0 = 0.f, acc1 = 0.f, acc2 = 0.f, acc3 = 0.f;
#pragma unroll
        for (int q = 0; q < 8; q++) {
            float4 hv = h4[q];
            acc0 = fmaf(hv.x, wk0[4 * q], acc0);
            acc1 = fmaf(hv.x, wk1[4 * q], acc1);
            acc2 = fmaf(hv.x, wk2[4 * q], acc2);
            acc3 = fmaf(hv.x, wk3[4 * q], acc3);
            acc0 = fmaf(hv.y, wk0[4 * q + 1], acc0);
            acc1 = fmaf(hv.y, wk1[4 * q + 1], acc1);
            acc2 = fmaf(hv.y, wk2[4 * q + 1], acc2);
            acc3 = fmaf(hv.y, wk3[4 * q + 1], acc3);
            acc0 = fmaf(hv.z, wk0[4 * q + 2], acc0);
            acc1 = fmaf(hv.z, wk1[4 * q + 2], acc1);
            acc2 = fmaf(hv.z, wk2[4 * q + 2], acc2);
            acc3 = fmaf(hv.z, wk3[4 * q + 2], acc3);
            acc0 = fmaf(hv.w, wk0[4 * q + 3], acc0);
            acc1 = fmaf(hv.w, wk1[4 * q + 3], acc1);
            acc2 = fmaf(hv.w, wk2[4 * q + 3], acc2);
            acc3 = fmaf(hv.w, wk3[4 * q + 3], acc3);
        }
        acc0 += eb0; acc1 += eb1; acc2 += eb2; acc3 += eb3;

        // activations: g0 = sigmoid (i|f); g2 = sigmoid (ib|fb);
        // g1 = tanh (z) for lo, sigmoid (o) for hi; g3 = softplus (d), lo only
        float g0 = sigmoidf_(acc0);
        float g2 = sigmoidf_(acc2);
        float y1 = lo ? 2.f * acc1 : acc1;
        float s1 = sigmoidf_(y1);
        float g1 = lo ? 2.f * s1 - 1.f : s1;   // tanh(x) = 2*sigmoid(2x)-1
        float g3 = softplusf(acc3);

        // redistribute: lane j<32 gets f,o,fb from lane j+32
        float f_  = __shfl_xor(g0, 32);
        float o_  = __shfl_xor(g1, 32);
        float fb_ = __shfl_xor(g2, 32);

        if (lo) {
            float cc = fmaf(f_, c_m, g0 * g1);       // c = f*c_m + i*z
            float cb = fmaf(fb_, cb_m, g2 * g1);     // cbar = fb*cbar_m + ib*z
            float e  = expf(-g3 * dt);
            float cn = cb + (cc - cb) * e;
            float h  = o_ * tanhf(cn);
            c_m = cn; cb_m = cb;
            h_s[l] = h;
            float* row = ccdo_base + t * 128;
            row[l] = cc; row[HH + l] = cb; row[2 * HH + l] = g3; row[3 * HH + l] = o_;
            h_base[t * HH + l] = h;
        }
    }
}

// ---------------- K2: lambda_sample + per-batch integral (1 block per b, no atomics) ----------------
__global__ __launch_bounds__(256) void k2_sample(const float* __restrict__ dts,
                                                 const float* __restrict__ msk,
                                                 const float* __restrict__ Wl,
                                                 float* ws,
                                                 float* __restrict__ out) {
    __shared__ float wlT[HH * EVN];  // wlT[k][e] = Wl[e][k]
    __shared__ float sh_s[8][HH];
    __shared__ float redn[8], redd[8];
    const int tid = threadIdx.x;
    const int b = blockIdx.x;
    for (int idx = tid; idx < EVN * HH; idx += 256) {
        int k = idx >> 5, e = idx & 31;
        wlT[idx] = Wl[e * HH + k];
    }
    const int rowg = tid >> 5, lane = tid & 31;
    float accn = 0.f, accd = 0.f;
    __syncthreads();

    for (int it = 0; it < SS / 8; it++) {
        const size_t rr = (size_t)b * SS + it * 8 + rowg;
        const float* row = ws + rr * 128;
        float c = row[lane], cb = row[HH + lane], dl = row[2 * HH + lane], o = row[3 * HH + lane];
        float e_ = expf(-dl * dts[rr]);
        float cd = cb + (c - cb) * e_;
        // sh_s[rowg][*] written+read by the same 32-lane half-wave: no barrier needed
        sh_s[rowg][lane] = o * tanhf(cd);
        float acc = 0.f;
#pragma unroll
        for (int k = 0; k < HH; k++) acc = fmaf(sh_s[rowg][k], wlT[k * EVN + lane], acc);
        float sp = softplusf(acc);
        out[2 + rr * EVN + lane] = sp;
        float ls = sp;
#pragma unroll
        for (int m = 16; m >= 1; m >>= 1) ls += __shfl_xor(ls, m, 32);
        float m_ = msk[rr];
        accn = fmaf(ls, m_, accn);   // same value on all 32 lanes
        accd += m_;
    }
    if (lane == 0) { redn[rowg] = accn; redd[rowg] = accd; }
    __syncthreads();
    if (tid == 0) {
        float n = 0.f, d = 0.f;
#pragma unroll
        for (int g = 0; g < 8; g++) { n += redn[g]; d += redd[g]; }
        ws[ACC_F + b] = n;
        ws[ACC_F + 256 + b] = d;
    }
}

// ---------------- K3: log-lambda at target + event count (1 block per b, no atomics) ----------------
__global__ __launch_bounds__(256) void k3_loglam(const int* __restrict__ event,
                                                 const float* __restrict__ Wl,
                                                 float* ws) {
    __shared__ float wl_s[EVN * HH];
    __shared__ float redl[8], redc[8];
    const int tid = threadIdx.x;
    const int b = blockIdx.x;
    for (int idx = tid; idx < EVN * HH; idx += 256) wl_s[idx] = Wl[idx];
    const int rowg = tid >> 5, lane = tid & 31;
    float accl = 0.f, accc = 0.f;
    __syncthreads();

    for (int t = rowg; t < TP1; t += 8) {
        int tgt = event[b * T2C + t + 1];
        if (tgt < EVN) {
            const float* hrow = ws + H_F + ((size_t)b * TP1 + t) * HH;
            float p = hrow[lane] * wl_s[tgt * HH + lane];
#pragma unroll
            for (int m = 16; m >= 1; m >>= 1) p += __shfl_xor(p, m, 32);
            accl += logf(softplusf(p) + EPSF);  // same on all lanes
            accc += 1.f;
        }
    }
    if (lane == 0) { redl[rowg] = accl; redc[rowg] = accc; }
    __syncthreads();
    if (tid == 0) {
        float l = 0.f, c = 0.f;
#pragma unroll
        for (int g = 0; g < 8; g++) { l += redl[g]; c += redc[g]; }
        ws[ACC_F + 512 + b] = l;
        ws[ACC_F + 768 + b] = c;
    }
}

// ---------------- K4: final reduction ----------------
__global__ __launch_bounds__(256) void k4_final(const float* __restrict__ duration,
                                                float* ws,
                                                float* __restrict__ out) {
    __shared__ float r1[256], r2[256];
    int tid = threadIdx.x;
    float nmr = ws[ACC_F + tid];
    float den = ws[ACC_F + 256 + tid];
    float llb = ws[ACC_F + 512 + tid];
    float nev = ws[ACC_F + 768 + tid];
    float obj = (nmr / den) * duration[tid] - llb;  // integral_b - sum_t loglam
    r1[tid] = obj;
    r2[tid] = nev;
    __syncthreads();
    for (int ofs = 128; ofs > 0; ofs >>= 1) {
        if (tid < ofs) { r1[tid] += r1[tid + ofs]; r2[tid] += r2[tid + ofs]; }
        __syncthreads();
    }
    if (tid == 0) { out[0] = r1[0]; out[1] = r2[0]; }
}

extern "C" void kernel_launch(void* const* d_in, const int* in_sizes, int n_in,
                              void* d_out, int out_size, void* d_ws, size_t ws_size,
                              hipStream_t stream) {
    const int*   event    = (const int*)d_in[0];
    const float* dtime    = (const float*)d_in[1];
    const float* duration = (const float*)d_in[2];
    const float* dts      = (const float*)d_in[3];
    // d_in[4] index_of_hidden_sampling: dead in reference
    const float* msk      = (const float*)d_in[5];
    const float* Emb      = (const float*)d_in[6];
    const float* W        = (const float*)d_in[7];
    const float* bias     = (const float*)d_in[8];
    const float* Wl       = (const float*)d_in[9];
    float* out = (float*)d_out;
    float* ws  = (float*)d_ws;

    k0_embw<<<1, 256, 0, stream>>>(Emb, W, bias, ws);
    k1_recur<<<BB, 64, 0, stream>>>(event, dtime, ws);
    k2_sample<<<BB, 256, 0, stream>>>(dts, msk, Wl, ws, out);
    k3_loglam<<<BB, 256, 0, stream>>>(event, Wl, ws);
    k4_final<<<1, 256, 0, stream>>>(duration, ws, out);
}

// Round 4
// 689.706 us; speedup vs baseline: 1.7466x; 1.7466x over previous
//
#include <hip/hip_runtime.h>
#include <hip/hip_bf16.h>
#include <math.h>

// Problem constants
#define BB 256
#define T2C 1026
#define TP1 1025
#define SS 1024
#define HH 32
#define EVN 32
#define VOCAB 35
#define NH7 224            // 7*H
#define NROWS 262400       // B*Tp1
#define EPSF 2.220446049250313e-16f

// ws layout in floats:
//  [0, NROWS*128)          ccdo rows: per (b,t): interleaved j*4 + {c,cbar,delta,o}
//  [H_F, +NROWS*32)        h rows
//  [EMBW_F, +35*224)       EmbW (x@W[:32,:] + b per vocab word)
//  [ACC_F, +2048)          per-(b,half): numer[512] | den[512] | loglam[512] | nev[512]
//  [W2T_F, +224*32)        W2 transposed: W2T[col][k] = W[(32+k)*224 + col]
#define H_F    ((size_t)NROWS * 128)               // 33,587,200
#define EMBW_F (H_F + (size_t)NROWS * HH)          // 41,984,000
#define ACC_F  (EMBW_F + (size_t)VOCAB * NH7)      // 41,991,840
#define NUM0   (ACC_F)
#define DEN0   (ACC_F + 512)
#define LL0    (ACC_F + 1024)
#define NEV0   (ACC_F + 1536)
#define W2T_F  (ACC_F + 2048)

__device__ __forceinline__ float rcp_(float x) { return __builtin_amdgcn_rcpf(x); }
__device__ __forceinline__ float sig_(float x) { return rcp_(1.f + __expf(-x)); }
__device__ __forceinline__ float tanh_(float x) { return fmaf(2.f, rcp_(1.f + __expf(-2.f * x)), -1.f); }
__device__ __forceinline__ float softplus_(float x) {
    return fmaxf(x, 0.f) + __logf(1.f + __expf(-fabsf(x)));
}

// ---------------- K0: EmbW precompute + W2 transpose ----------------
__global__ __launch_bounds__(256) void k0_embw(const float* __restrict__ Emb,
                                               const float* __restrict__ W,
                                               const float* __restrict__ bias,
                                               float* __restrict__ ws) {
    int j = threadIdx.x;
    __shared__ float embs[VOCAB * HH];
    for (int idx = j; idx < VOCAB * HH; idx += 256) embs[idx] = Emb[idx];
    // W2T[c][k] = W[(32+k)*224 + c]
    for (int idx = j; idx < NH7 * HH; idx += 256) {
        int c = idx >> 5, k = idx & 31;
        ws[W2T_F + idx] = W[(HH + k) * NH7 + c];
    }
    __syncthreads();
    if (j < NH7) {
        for (int v = 0; v < VOCAB; v++) {
            float s = bias[j];
#pragma unroll
            for (int k = 0; k < HH; k++) s = fmaf(embs[v * HH + k], W[k * NH7 + j], s);
            ws[EMBW_F + v * NH7 + j] = s;
        }
    }
}

// ---------------- K1: sequential CTLSTM scan — ONE WAVE per batch, no barriers ----------------
// Lane l owns columns {l, l+64, l+128, l+192(lo only)}:
//   l<32 : gates i(c0), z(c1), ib(c2), d(c3) of hidden j=l
//   l>=32: gates f(c0), o(c1), fb(c2)        of hidden j=l-32
__global__ __launch_bounds__(64) void k1_recur(const int* __restrict__ event,
                                               const float* __restrict__ dtime,
                                               float* ws) {
    const int b = blockIdx.x;
    const int l = threadIdx.x;  // 0..63
    __shared__ float embw[VOCAB * NH7];
    __shared__ float dt_s[TP1];
    __shared__ int ev_s[TP1 + 1];
    __shared__ __align__(16) float h_s[HH];

    for (int idx = l; idx < VOCAB * NH7; idx += 64) embw[idx] = ws[EMBW_F + idx];
    for (int idx = l; idx < TP1 + 1; idx += 64) {
        ev_s[idx] = (idx < TP1) ? event[b * T2C + idx] : 0;
        if (idx < TP1) dt_s[idx] = dtime[b * T2C + idx + 1];
    }
    if (l < HH) h_s[l] = 0.f;

    const bool lo = (l < HH);
    const int c0 = l, c1 = l + 64, c2 = l + 128;
    const int c3 = lo ? (l + 192) : l;  // clamp for hi lanes (value unused)
    // W2 columns into registers (vectorized from W2T staged by k0)
    float wk0[HH], wk1[HH], wk2[HH], wk3[HH];
    {
        const float4* w2t = (const float4*)(ws + W2T_F);
#pragma unroll
        for (int q = 0; q < 8; q++) {
            float4 a = w2t[c0 * 8 + q];
            wk0[4 * q] = a.x; wk0[4 * q + 1] = a.y; wk0[4 * q + 2] = a.z; wk0[4 * q + 3] = a.w;
            float4 bq = w2t[c1 * 8 + q];
            wk1[4 * q] = bq.x; wk1[4 * q + 1] = bq.y; wk1[4 * q + 2] = bq.z; wk1[4 * q + 3] = bq.w;
            float4 cq = w2t[c2 * 8 + q];
            wk2[4 * q] = cq.x; wk2[4 * q + 1] = cq.y; wk2[4 * q + 2] = cq.z; wk2[4 * q + 3] = cq.w;
            float4 dq = lo ? w2t[c3 * 8 + q] : make_float4(0.f, 0.f, 0.f, 0.f);
            wk3[4 * q] = dq.x; wk3[4 * q + 1] = dq.y; wk3[4 * q + 2] = dq.z; wk3[4 * q + 3] = dq.w;
        }
    }
    float c_m = 0.f, cb_m = 0.f;
    float* ccdo_base = ws + (size_t)b * TP1 * 128;
    float* h_base = ws + H_F + (size_t)b * TP1 * HH;
    __syncthreads();

    int ev = ev_s[0];
    for (int t = 0; t < TP1; t++) {
        // EmbW contribution folded into chain start (LDS reads issued first)
        const float* eb = embw + ev * NH7;
        float a0 = eb[c0], a1 = eb[c1], a2 = eb[c2], a3 = lo ? eb[c3] : 0.f;
        ev = ev_s[t + 1];
        float dt = dt_s[t];

        // h broadcast read; two 16-deep partial chains per dot for lower dep latency
        const float4* h4 = (const float4*)h_s;
        float p0 = 0.f, p1 = 0.f, p2 = 0.f, p3 = 0.f;
#pragma unroll
        for (int q = 0; q < 4; q++) {
            float4 hv = h4[q];
            a0 = fmaf(hv.x, wk0[4 * q], a0);     a1 = fmaf(hv.x, wk1[4 * q], a1);
            a2 = fmaf(hv.x, wk2[4 * q], a2);     a3 = fmaf(hv.x, wk3[4 * q], a3);
            a0 = fmaf(hv.y, wk0[4 * q + 1], a0); a1 = fmaf(hv.y, wk1[4 * q + 1], a1);
            a2 = fmaf(hv.y, wk2[4 * q + 1], a2); a3 = fmaf(hv.y, wk3[4 * q + 1], a3);
            a0 = fmaf(hv.z, wk0[4 * q + 2], a0); a1 = fmaf(hv.z, wk1[4 * q + 2], a1);
            a2 = fmaf(hv.z, wk2[4 * q + 2], a2); a3 = fmaf(hv.z, wk3[4 * q + 2], a3);
            a0 = fmaf(hv.w, wk0[4 * q + 3], a0); a1 = fmaf(hv.w, wk1[4 * q + 3], a1);
            a2 = fmaf(hv.w, wk2[4 * q + 3], a2); a3 = fmaf(hv.w, wk3[4 * q + 3], a3);
        }
#pragma unroll
        for (int q = 4; q < 8; q++) {
            float4 hv = h4[q];
            p0 = fmaf(hv.x, wk0[4 * q], p0);     p1 = fmaf(hv.x, wk1[4 * q], p1);
            p2 = fmaf(hv.x, wk2[4 * q], p2);     p3 = fmaf(hv.x, wk3[4 * q], p3);
            p0 = fmaf(hv.y, wk0[4 * q + 1], p0); p1 = fmaf(hv.y, wk1[4 * q + 1], p1);
            p2 = fmaf(hv.y, wk2[4 * q + 1], p2); p3 = fmaf(hv.y, wk3[4 * q + 1], p3);
            p0 = fmaf(hv.z, wk0[4 * q + 2], p0); p1 = fmaf(hv.z, wk1[4 * q + 2], p1);
            p2 = fmaf(hv.z, wk2[4 * q + 2], p2); p3 = fmaf(hv.z, wk3[4 * q + 2], p3);
            p0 = fmaf(hv.w, wk0[4 * q + 3], p0); p1 = fmaf(hv.w, wk1[4 * q + 3], p1);
            p2 = fmaf(hv.w, wk2[4 * q + 3], p2); p3 = fmaf(hv.w, wk3[4 * q + 3], p3);
        }
        float acc0 = a0 + p0, acc1 = a1 + p1, acc2 = a2 + p2, acc3 = a3 + p3;

        // fast activations
        float g0 = sig_(acc0);                       // i | f
        float g2 = sig_(acc2);                       // ib | fb
        float y1 = lo ? acc1 + acc1 : acc1;
        float s1 = sig_(y1);
        float g1 = lo ? fmaf(2.f, s1, -1.f) : s1;    // tanh(z) | sigmoid(o)
        float g3 = softplus_(acc3);                  // delta (lo only)

        float f_  = __shfl_xor(g0, 32);
        float o_  = __shfl_xor(g1, 32);
        float fb_ = __shfl_xor(g2, 32);

        if (lo) {
            float cc = fmaf(f_, c_m, g0 * g1);
            float cb = fmaf(fb_, cb_m, g2 * g1);
            float e  = __expf(-g3 * dt);
            float cn = fmaf(cc - cb, e, cb);
            float h  = o_ * tanh_(cn);
            c_m = cn; cb_m = cb;
            h_s[l] = h;
            float4 st = make_float4(cc, cb, g3, o_);
            ((float4*)(ccdo_base + (size_t)t * 128))[l] = st;   // one dwordx4 store
            h_base[t * HH + l] = h;
        }
    }
}

// ---------------- K2: lambda_sample + per-batch integral (grid 256x2, no atomics) ----------------
__global__ __launch_bounds__(256) void k2_sample(const float* __restrict__ dts,
                                                 const float* __restrict__ msk,
                                                 const float* __restrict__ Wl,
                                                 float* ws,
                                                 float* __restrict__ out) {
    __shared__ __align__(16) float sh_s[8][HH];
    __shared__ float redn[8], redd[8];
    const int tid = threadIdx.x;
    const int b = blockIdx.x, half = blockIdx.y;
    const int rowg = tid >> 5, lane = tid & 31;
    // Wl row `lane` in registers
    float4 wl4[8];
#pragma unroll
    for (int q = 0; q < 8; q++) wl4[q] = ((const float4*)(Wl + lane * HH))[q];

    const int base = b * SS + half * 512;
    float accn = 0.f, accd = 0.f;

#pragma unroll 2
    for (int it = 0; it < 64; it++) {
        const size_t rr = (size_t)base + it * 8 + rowg;
        float4 v = *(const float4*)(ws + rr * 128 + lane * 4);  // c, cbar, delta, o
        float e_ = __expf(-v.z * dts[rr]);
        float cd = fmaf(v.x - v.y, e_, v.y);
        // sh_s row written+read by the same wave: no barrier needed
        sh_s[rowg][lane] = v.w * tanh_(cd);
        const float4* sh4 = (const float4*)sh_s[rowg];
        float acc = 0.f, acc2 = 0.f;
#pragma unroll
        for (int q = 0; q < 4; q++) {
            float4 s4 = sh4[q];
            acc  = fmaf(s4.x, wl4[q].x, acc);  acc  = fmaf(s4.y, wl4[q].y, acc);
            acc  = fmaf(s4.z, wl4[q].z, acc);  acc  = fmaf(s4.w, wl4[q].w, acc);
        }
#pragma unroll
        for (int q = 4; q < 8; q++) {
            float4 s4 = sh4[q];
            acc2 = fmaf(s4.x, wl4[q].x, acc2); acc2 = fmaf(s4.y, wl4[q].y, acc2);
            acc2 = fmaf(s4.z, wl4[q].z, acc2); acc2 = fmaf(s4.w, wl4[q].w, acc2);
        }
        float sp = softplus_(acc + acc2);
        out[2 + rr * EVN + lane] = sp;
        float ls = sp;
#pragma unroll
        for (int m = 16; m >= 1; m >>= 1) ls += __shfl_xor(ls, m);
        float m_ = msk[rr];
        accn = fmaf(ls, m_, accn);
        accd += m_;
    }
    if (lane == 0) { redn[rowg] = accn; redd[rowg] = accd; }
    __syncthreads();
    if (tid == 0) {
        float n = 0.f, d = 0.f;
#pragma unroll
        for (int g = 0; g < 8; g++) { n += redn[g]; d += redd[g]; }
        ws[NUM0 + half * 256 + b] = n;
        ws[DEN0 + half * 256 + b] = d;
    }
}

// ---------------- K3: log-lambda at target + event count (grid 256x2, no atomics) ----------------
__global__ __launch_bounds__(256) void k3_loglam(const int* __restrict__ event,
                                                 const float* __restrict__ Wl,
                                                 float* ws) {
    __shared__ float wl_s[EVN * HH];
    __shared__ float redl[8], redc[8];
    const int tid = threadIdx.x;
    const int b = blockIdx.x, half = blockIdx.y;
    for (int idx = tid; idx < EVN * HH; idx += 256) wl_s[idx] = Wl[idx];
    const int rowg = tid >> 5, lane = tid & 31;
    const int t_end = half ? TP1 : 512;
    float accl = 0.f, accc = 0.f;
    __syncthreads();

    for (int t = 512 * half + rowg; t < t_end; t += 8) {
        int tgt = event[b * T2C + t + 1];
        if (tgt < EVN) {
            const float* hrow = ws + H_F + ((size_t)b * TP1 + t) * HH;
            float p = hrow[lane] * wl_s[tgt * HH + lane];
#pragma unroll
            for (int m = 16; m >= 1; m >>= 1) p += __shfl_xor(p, m);
            accl += __logf(softplus_(p) + EPSF);
            accc += 1.f;
        }
    }
    if (lane == 0) { redl[rowg] = accl; redc[rowg] = accc; }
    __syncthreads();
    if (tid == 0) {
        float l = 0.f, c = 0.f;
#pragma unroll
        for (int g = 0; g < 8; g++) { l += redl[g]; c += redc[g]; }
        ws[LL0 + half * 256 + b] = l;
        ws[NEV0 + half * 256 + b] = c;
    }
}

// ---------------- K4: final reduction ----------------
__global__ __launch_bounds__(256) void k4_final(const float* __restrict__ duration,
                                                float* ws,
                                                float* __restrict__ out) {
    __shared__ float r1[256], r2[256];
    int tid = threadIdx.x;
    float nmr = ws[NUM0 + tid] + ws[NUM0 + 256 + tid];
    float den = ws[DEN0 + tid] + ws[DEN0 + 256 + tid];
    float llb = ws[LL0 + tid] + ws[LL0 + 256 + tid];
    float nev = ws[NEV0 + tid] + ws[NEV0 + 256 + tid];
    r1[tid] = (nmr / den) * duration[tid] - llb;
    r2[tid] = nev;
    __syncthreads();
    for (int ofs = 128; ofs > 0; ofs >>= 1) {
        if (tid < ofs) { r1[tid] += r1[tid + ofs]; r2[tid] += r2[tid + ofs]; }
        __syncthreads();
    }
    if (tid == 0) { out[0] = r1[0]; out[1] = r2[0]; }
}

extern "C" void kernel_launch(void* const* d_in, const int* in_sizes, int n_in,
                              void* d_out, int out_size, void* d_ws, size_t ws_size,
                              hipStream_t stream) {
    const int*   event    = (const int*)d_in[0];
    const float* dtime    = (const float*)d_in[1];
    const float* duration = (const float*)d_in[2];
    const float* dts      = (const float*)d_in[3];
    // d_in[4] index_of_hidden_sampling: dead in reference
    const float* msk      = (const float*)d_in[5];
    const float* Emb      = (const float*)d_in[6];
    const float* W        = (const float*)d_in[7];
    const float* bias     = (const float*)d_in[8];
    const float* Wl       = (const float*)d_in[9];
    float* out = (float*)d_out;
    float* ws  = (float*)d_ws;

    k0_embw<<<1, 256, 0, stream>>>(Emb, W, bias, ws);
    k1_recur<<<BB, 64, 0, stream>>>(event, dtime, ws);
    k2_sample<<<dim3(BB, 2), 256, 0, stream>>>(dts, msk, Wl, ws, out);
    k3_loglam<<<dim3(BB, 2), 256, 0, stream>>>(event, Wl, ws);
    k4_final<<<1, 256, 0, stream>>>(duration, ws, out);
}

// Round 5
// 674.158 us; speedup vs baseline: 1.7869x; 1.0231x over previous
//
#include <hip/hip_runtime.h>
#include <hip/hip_bf16.h>
#include <math.h>

// Problem constants
#define BB 256
#define T2C 1026
#define TP1 1025
#define SS 1024
#define HH 32
#define EVN 32
#define VOCAB 35
#define NH7 224            // 7*H
#define NROWS 262400       // B*Tp1
#define EPSF 2.220446049250313e-16f

// ws layout in floats:
//  [0, NROWS*128)          ccdo rows: per (b,t): interleaved j*4 + {c,cbar,delta,o}
//  [EMBW_F, +35*224)       EmbW (x@W[:32,:] + b per vocab word)
//  [ACC_F, +4096)          per-(b,quarter): numer[1024] | den[1024] | loglam[1024] | nev[1024]
//  [W2T_F, +224*32)        W2 transposed: W2T[col][k] = W[(32+k)*224 + col]
#define EMBW_F ((size_t)NROWS * 128)               // 33,587,200
#define ACC_F  (EMBW_F + (size_t)VOCAB * NH7)
#define NUM0   (ACC_F)
#define DEN0   (ACC_F + 1024)
#define LL0    (ACC_F + 2048)
#define NEV0   (ACC_F + 3072)
#define W2T_F  (ACC_F + 4096)

__device__ __forceinline__ float rcp_(float x) { return __builtin_amdgcn_rcpf(x); }
__device__ __forceinline__ float sig_(float x) { return rcp_(1.f + __expf(-x)); }
__device__ __forceinline__ float tanh_(float x) { return fmaf(2.f, rcp_(1.f + __expf(-2.f * x)), -1.f); }
__device__ __forceinline__ float softplus_(float x) {
    return fmaxf(x, 0.f) + __logf(1.f + __expf(-fabsf(x)));
}
// lo lanes (l<32) receive x from lane l+32 (hi lanes get undefined-but-harmless)
__device__ __forceinline__ float swap_hi_to_lo(float x) {
    float a = x, b = x;
    asm volatile("v_permlane32_swap_b32 %0, %1" : "+v"(a), "+v"(b));
    return a;  // lanes 0..31: old b[lane+32] = x[lane+32]
}

// ---------------- K0: EmbW precompute + W2 transpose ----------------
__global__ __launch_bounds__(256) void k0_embw(const float* __restrict__ Emb,
                                               const float* __restrict__ W,
                                               const float* __restrict__ bias,
                                               float* __restrict__ ws) {
    int j = threadIdx.x;
    __shared__ float embs[VOCAB * HH];
    for (int idx = j; idx < VOCAB * HH; idx += 256) embs[idx] = Emb[idx];
    for (int idx = j; idx < NH7 * HH; idx += 256) {
        int c = idx >> 5, k = idx & 31;
        ws[W2T_F + idx] = W[(HH + k) * NH7 + c];
    }
    __syncthreads();
    if (j < NH7) {
        for (int v = 0; v < VOCAB; v++) {
            float s = bias[j];
#pragma unroll
            for (int k = 0; k < HH; k++) s = fmaf(embs[v * HH + k], W[k * NH7 + j], s);
            ws[EMBW_F + v * NH7 + j] = s;
        }
    }
}

// ---------------- K1: sequential CTLSTM scan — ONE WAVE per batch ----------------
// No LDS writes in the loop: h broadcast via v_readlane (SGPRs),
// half-swap via v_permlane32_swap_b32. eb/dt/ev prefetched one step ahead.
// Lane l owns columns {l, l+64, l+128, l+192(lo only)}:
//   l<32 : gates i(c0), z(c1), ib(c2), d(c3) of hidden j=l
//   l>=32: gates f(c0), o(c1), fb(c2)        of hidden j=l-32
__global__ __launch_bounds__(64) void k1_recur(const int* __restrict__ event,
                                               const float* __restrict__ dtime,
                                               float* ws) {
    const int b = blockIdx.x;
    const int l = threadIdx.x;  // 0..63
    __shared__ float embw[VOCAB * NH7];
    __shared__ float dt_s[TP1 + 1];
    __shared__ int ev_s[TP1 + 1];

    for (int idx = l; idx < VOCAB * NH7; idx += 64) embw[idx] = ws[EMBW_F + idx];
    for (int idx = l; idx < TP1; idx += 64) {
        ev_s[idx] = event[b * T2C + idx];
        dt_s[idx] = dtime[b * T2C + idx + 1];
    }
    if (l == 0) { ev_s[TP1] = 0; dt_s[TP1] = 0.f; }

    const bool lo = (l < HH);
    const int c0 = l, c1 = l + 64, c2 = l + 128;
    const int c3 = lo ? (l + 192) : l;  // clamped for hi (value zeroed below)
    float wk0[HH], wk1[HH], wk2[HH], wk3[HH];
    {
        const float4* w2t = (const float4*)(ws + W2T_F);
#pragma unroll
        for (int q = 0; q < 8; q++) {
            float4 a = w2t[c0 * 8 + q];
            wk0[4 * q] = a.x; wk0[4 * q + 1] = a.y; wk0[4 * q + 2] = a.z; wk0[4 * q + 3] = a.w;
            float4 bq = w2t[c1 * 8 + q];
            wk1[4 * q] = bq.x; wk1[4 * q + 1] = bq.y; wk1[4 * q + 2] = bq.z; wk1[4 * q + 3] = bq.w;
            float4 cq = w2t[c2 * 8 + q];
            wk2[4 * q] = cq.x; wk2[4 * q + 1] = cq.y; wk2[4 * q + 2] = cq.z; wk2[4 * q + 3] = cq.w;
            float4 dq = lo ? w2t[c3 * 8 + q] : make_float4(0.f, 0.f, 0.f, 0.f);
            wk3[4 * q] = dq.x; wk3[4 * q + 1] = dq.y; wk3[4 * q + 2] = dq.z; wk3[4 * q + 3] = dq.w;
        }
    }
    float* ccdo_base = ws + (size_t)b * TP1 * 128;
    __syncthreads();

    float hprev = 0.f, c_m = 0.f, cb_m = 0.f;
    // prologue prefetch for t=0
    int ev0 = ev_s[0];
    const float* ebp = embw + ev0 * NH7;
    float eb0 = ebp[c0], eb1 = ebp[c1], eb2 = ebp[c2], eb3 = lo ? ebp[c3] : 0.f;
    float dtc = dt_s[0];

    for (int t = 0; t < TP1; t++) {
        float a0 = eb0, a1 = eb1, a2 = eb2, a3 = eb3;
        const float dt = dtc;
        // prefetch step t+1 (independent; hides LDS latency under GEMV)
        {
            int evn = ev_s[t + 1];
            const float* ebn = embw + evn * NH7;
            eb0 = ebn[c0]; eb1 = ebn[c1]; eb2 = ebn[c2]; eb3 = lo ? ebn[c3] : 0.f;
            dtc = dt_s[t + 1];
        }
        // broadcast h via readlane -> uniform scalars
        float s_h[HH];
#pragma unroll
        for (int k = 0; k < HH; k++)
            s_h[k] = __uint_as_float(__builtin_amdgcn_readlane(__float_as_uint(hprev), k));
        // GEMV: 4 independent 32-deep chains (issue-bound)
#pragma unroll
        for (int k = 0; k < HH; k++) {
            a0 = fmaf(s_h[k], wk0[k], a0);
            a1 = fmaf(s_h[k], wk1[k], a1);
            a2 = fmaf(s_h[k], wk2[k], a2);
            a3 = fmaf(s_h[k], wk3[k], a3);
        }
        // activations
        float g0 = sig_(a0);                       // i | f
        float g2 = sig_(a2);                       // ib | fb
        float y1 = lo ? a1 + a1 : a1;
        float s1 = sig_(y1);
        float g1 = lo ? fmaf(2.f, s1, -1.f) : s1;  // tanh(z) | sigmoid(o)
        float g3 = softplus_(a3);                  // delta (valid on lo)
        float e  = __expf(-g3 * dt);               // ready early, off gate path
        // hi -> lo half swap (VALU permlane, no LDS)
        float f_  = swap_hi_to_lo(g0);
        float o_  = swap_hi_to_lo(g1);
        float fb_ = swap_hi_to_lo(g2);
        // update (all lanes execute; hi lanes produce garbage, never read)
        float cc = fmaf(f_, c_m, g0 * g1);
        float cb = fmaf(fb_, cb_m, g2 * g1);
        float cn = fmaf(cc - cb, e, cb);
        float hn = o_ * tanh_(cn);
        c_m = cn; cb_m = cb;
        if (lo)
            ((float4*)(ccdo_base + (size_t)t * 128))[l] = make_float4(cc, cb, g3, o_);
        hprev = hn;
    }
}

// ---------------- K2: lambda_sample + per-batch integral (grid 256x4, no atomics) ----------------
__global__ __launch_bounds__(256) void k2_sample(const float* __restrict__ dts,
                                                 const float* __restrict__ msk,
                                                 const float* __restrict__ Wl,
                                                 float* ws,
                                                 float* __restrict__ out) {
    __shared__ __align__(16) float sh_s[8][HH];
    __shared__ float redn[8], redd[8];
    const int tid = threadIdx.x;
    const int b = blockIdx.x, q4 = blockIdx.y;
    const int rowg = tid >> 5, lane = tid & 31;
    float4 wl4[8];
#pragma unroll
    for (int q = 0; q < 8; q++) wl4[q] = ((const float4*)(Wl + lane * HH))[q];

    const int base = b * SS + q4 * 256;
    float accn = 0.f, accd = 0.f;

#pragma unroll 2
    for (int it = 0; it < 32; it++) {
        const size_t rr = (size_t)base + it * 8 + rowg;
        float4 v = *(const float4*)(ws + rr * 128 + lane * 4);  // c, cbar, delta, o
        float e_ = __expf(-v.z * dts[rr]);
        float cd = fmaf(v.x - v.y, e_, v.y);
        sh_s[rowg][lane] = v.w * tanh_(cd);   // same-wave write/read, no barrier
        const float4* sh4 = (const float4*)sh_s[rowg];
        float acc = 0.f, acc2 = 0.f;
#pragma unroll
        for (int q = 0; q < 4; q++) {
            float4 s4 = sh4[q];
            acc  = fmaf(s4.x, wl4[q].x, acc);  acc  = fmaf(s4.y, wl4[q].y, acc);
            acc  = fmaf(s4.z, wl4[q].z, acc);  acc  = fmaf(s4.w, wl4[q].w, acc);
        }
#pragma unroll
        for (int q = 4; q < 8; q++) {
            float4 s4 = sh4[q];
            acc2 = fmaf(s4.x, wl4[q].x, acc2); acc2 = fmaf(s4.y, wl4[q].y, acc2);
            acc2 = fmaf(s4.z, wl4[q].z, acc2); acc2 = fmaf(s4.w, wl4[q].w, acc2);
        }
        float sp = softplus_(acc + acc2);
        out[2 + rr * EVN + lane] = sp;
        float ls = sp;
#pragma unroll
        for (int m = 16; m >= 1; m >>= 1) ls += __shfl_xor(ls, m);
        float m_ = msk[rr];
        accn = fmaf(ls, m_, accn);
        accd += m_;
    }
    if (lane == 0) { redn[rowg] = accn; redd[rowg] = accd; }
    __syncthreads();
    if (tid == 0) {
        float n = 0.f, d = 0.f;
#pragma unroll
        for (int g = 0; g < 8; g++) { n += redn[g]; d += redd[g]; }
        ws[NUM0 + q4 * 256 + b] = n;
        ws[DEN0 + q4 * 256 + b] = d;
    }
}

// ---------------- K3: log-lambda at target (recomputes h from ccdo) ----------------
__global__ __launch_bounds__(256) void k3_loglam(const int* __restrict__ event,
                                                 const float* __restrict__ dtime,
                                                 const float* __restrict__ Wl,
                                                 float* ws) {
    __shared__ float wl_s[EVN * HH];
    __shared__ float redl[8], redc[8];
    const int tid = threadIdx.x;
    const int b = blockIdx.x, q4 = blockIdx.y;
    for (int idx = tid; idx < EVN * HH; idx += 256) wl_s[idx] = Wl[idx];
    const int rowg = tid >> 5, lane = tid & 31;
    const int t_end = (q4 < 3) ? (q4 + 1) * 256 : TP1;
    float accl = 0.f, accc = 0.f;
    __syncthreads();

    for (int t = q4 * 256 + rowg; t < t_end; t += 8) {
        int tgt = event[b * T2C + t + 1];
        if (tgt < EVN) {
            float4 v = *(const float4*)(ws + ((size_t)b * TP1 + t) * 128 + lane * 4);
            float dt = dtime[b * T2C + t + 1];
            float e_ = __expf(-v.z * dt);
            float cd = fmaf(v.x - v.y, e_, v.y);
            float h = v.w * tanh_(cd);
            float p = h * wl_s[tgt * HH + lane];
#pragma unroll
            for (int m = 16; m >= 1; m >>= 1) p += __shfl_xor(p, m);
            accl += __logf(softplus_(p) + EPSF);
            accc += 1.f;
        }
    }
    if (lane == 0) { redl[rowg] = accl; redc[rowg] = accc; }
    __syncthreads();
    if (tid == 0) {
        float l = 0.f, c = 0.f;
#pragma unroll
        for (int g = 0; g < 8; g++) { l += redl[g]; c += redc[g]; }
        ws[LL0 + q4 * 256 + b] = l;
        ws[NEV0 + q4 * 256 + b] = c;
    }
}

// ---------------- K4: final reduction ----------------
__global__ __launch_bounds__(256) void k4_final(const float* __restrict__ duration,
                                                float* ws,
                                                float* __restrict__ out) {
    __shared__ float r1[256], r2[256];
    int tid = threadIdx.x;
    float nmr = 0.f, den = 0.f, llb = 0.f, nev = 0.f;
#pragma unroll
    for (int q = 0; q < 4; q++) {
        nmr += ws[NUM0 + q * 256 + tid];
        den += ws[DEN0 + q * 256 + tid];
        llb += ws[LL0 + q * 256 + tid];
        nev += ws[NEV0 + q * 256 + tid];
    }
    r1[tid] = (nmr / den) * duration[tid] - llb;
    r2[tid] = nev;
    __syncthreads();
    for (int ofs = 128; ofs > 0; ofs >>= 1) {
        if (tid < ofs) { r1[tid] += r1[tid + ofs]; r2[tid] += r2[tid + ofs]; }
        __syncthreads();
    }
    if (tid == 0) { out[0] = r1[0]; out[1] = r2[0]; }
}

extern "C" void kernel_launch(void* const* d_in, const int* in_sizes, int n_in,
                              void* d_out, int out_size, void* d_ws, size_t ws_size,
                              hipStream_t stream) {
    const int*   event    = (const int*)d_in[0];
    const float* dtime    = (const float*)d_in[1];
    const float* duration = (const float*)d_in[2];
    const float* dts      = (const float*)d_in[3];
    // d_in[4] index_of_hidden_sampling: dead in reference
    const float* msk      = (const float*)d_in[5];
    const float* Emb      = (const float*)d_in[6];
    const float* W        = (const float*)d_in[7];
    const float* bias     = (const float*)d_in[8];
    const float* Wl       = (const float*)d_in[9];
    float* out = (float*)d_out;
    float* ws  = (float*)d_ws;

    k0_embw<<<1, 256, 0, stream>>>(Emb, W, bias, ws);
    k1_recur<<<BB, 64, 0, stream>>>(event, dtime, ws);
    k2_sample<<<dim3(BB, 4), 256, 0, stream>>>(dts, msk, Wl, ws, out);
    k3_loglam<<<dim3(BB, 4), 256, 0, stream>>>(event, dtime, Wl, ws);
    k4_final<<<1, 256, 0, stream>>>(duration, ws, out);
}

// Round 6
// 645.900 us; speedup vs baseline: 1.8651x; 1.0438x over previous
//
#include <hip/hip_runtime.h>
#include <hip/hip_bf16.h>
#include <math.h>

// Problem constants
#define BB 256
#define T2C 1026
#define TP1 1025
#define SS 1024
#define HH 32
#define EVN 32
#define VOCAB 35
#define NH7 224            // 7*H
#define NROWS 262400       // B*Tp1
#define EPSF 2.220446049250313e-16f

// ws layout in floats:
//  [0, NROWS*128)          ccdo rows: per (b,t): interleaved j*4 + {c,cbar,delta,o}
//  [EMBW_F, +35*224)       EmbW (x@W[:32,:] + b per vocab word)
//  [ACC_F, +4096)          per-(b,quarter): numer[1024] | den[1024] | loglam[1024] | nev[1024]
//  [W2T_F, +224*32)        W2 transposed: W2T[col][k] = W[(32+k)*224 + col]
#define EMBW_F ((size_t)NROWS * 128)               // 33,587,200
#define ACC_F  (EMBW_F + (size_t)VOCAB * NH7)
#define NUM0   (ACC_F)
#define DEN0   (ACC_F + 1024)
#define LL0    (ACC_F + 2048)
#define NEV0   (ACC_F + 3072)
#define W2T_F  (ACC_F + 4096)

__device__ __forceinline__ float rcp_(float x) { return __builtin_amdgcn_rcpf(x); }
__device__ __forceinline__ float sig_(float x) { return rcp_(1.f + __expf(-x)); }
__device__ __forceinline__ float tanh_(float x) { return fmaf(2.f, rcp_(1.f + __expf(-2.f * x)), -1.f); }
__device__ __forceinline__ float softplus_(float x) {
    return fmaxf(x, 0.f) + __logf(1.f + __expf(-fabsf(x)));
}
// lo lanes (l<32) receive x from lane l+32
__device__ __forceinline__ float swap_hi_to_lo(float x) {
    float a = x, b = x;
    asm volatile("v_permlane32_swap_b32 %0, %1" : "+v"(a), "+v"(b));
    return a;
}

// ---------------- K0: EmbW precompute + W2 transpose ----------------
__global__ __launch_bounds__(256) void k0_embw(const float* __restrict__ Emb,
                                               const float* __restrict__ W,
                                               const float* __restrict__ bias,
                                               float* __restrict__ ws) {
    int j = threadIdx.x;
    __shared__ float embs[VOCAB * HH];
    for (int idx = j; idx < VOCAB * HH; idx += 256) embs[idx] = Emb[idx];
    for (int idx = j; idx < NH7 * HH; idx += 256) {
        int c = idx >> 5, k = idx & 31;
        ws[W2T_F + idx] = W[(HH + k) * NH7 + c];
    }
    __syncthreads();
    if (j < NH7) {
        for (int v = 0; v < VOCAB; v++) {
            float s = bias[j];
#pragma unroll
            for (int k = 0; k < HH; k++) s = fmaf(embs[v * HH + k], W[k * NH7 + j], s);
            ws[EMBW_F + v * NH7 + j] = s;
        }
    }
}

// ---------------- K1: sequential CTLSTM scan — ONE WAVE per batch ----------------
// __launch_bounds__(64,1): full 512-VGPR budget so all 128 W-column values and
// temps stay in registers (R5's 132-VGPR allocation spilled W to scratch).
// Lane l owns columns {l, l+64, l+128, l+192(lo only)}:
//   l<32 : gates i(c0), z(c1), ib(c2), d(c3) of hidden j=l
//   l>=32: gates f(c0), o(c1), fb(c2)        of hidden j=l-32
__global__ __launch_bounds__(64, 1) void k1_recur(const int* __restrict__ event,
                                                  const float* __restrict__ dtime,
                                                  float* ws) {
    const int b = blockIdx.x;
    const int l = threadIdx.x;  // 0..63
    __shared__ __align__(16) float4 embp[VOCAB][64];  // per-lane packed EmbW
    __shared__ float dt_s[TP1 + 1];
    __shared__ int ev_s[TP1 + 1];

    const bool lo = (l < HH);
    const int c0 = l, c1 = l + 64, c2 = l + 128, c3 = l + 192;

    // packed per-lane EmbW table: one ds_read_b128 per step instead of 4 ds_read_b32
    for (int v = 0; v < VOCAB; v++) {
        const float* e = ws + EMBW_F + v * NH7;
        embp[v][l] = make_float4(e[c0], e[c1], e[c2], lo ? e[c3] : 0.f);
    }
    for (int idx = l; idx < TP1; idx += 64) {
        ev_s[idx] = event[b * T2C + idx];
        dt_s[idx] = dtime[b * T2C + idx + 1];
    }
    if (l == 0) { ev_s[TP1] = 0; dt_s[TP1] = 0.f; }

    float wk0[HH], wk1[HH], wk2[HH], wk3[HH];
    {
        const float4* w2t = (const float4*)(ws + W2T_F);
#pragma unroll
        for (int q = 0; q < 8; q++) {
            float4 a = w2t[c0 * 8 + q];
            wk0[4 * q] = a.x; wk0[4 * q + 1] = a.y; wk0[4 * q + 2] = a.z; wk0[4 * q + 3] = a.w;
            float4 bq = w2t[c1 * 8 + q];
            wk1[4 * q] = bq.x; wk1[4 * q + 1] = bq.y; wk1[4 * q + 2] = bq.z; wk1[4 * q + 3] = bq.w;
            float4 cq = w2t[c2 * 8 + q];
            wk2[4 * q] = cq.x; wk2[4 * q + 1] = cq.y; wk2[4 * q + 2] = cq.z; wk2[4 * q + 3] = cq.w;
            float4 dq = lo ? w2t[c3 * 8 + q] : make_float4(0.f, 0.f, 0.f, 0.f);
            wk3[4 * q] = dq.x; wk3[4 * q + 1] = dq.y; wk3[4 * q + 2] = dq.z; wk3[4 * q + 3] = dq.w;
        }
    }
    float* ccdo_base = ws + (size_t)b * TP1 * 128;
    __syncthreads();

    float hprev = 0.f, c_m = 0.f, cb_m = 0.f;
    float4 eb = embp[ev_s[0]][l];
    float dtc = dt_s[0];

    for (int t = 0; t < TP1; t++) {
        float a0 = eb.x, a1 = eb.y, a2 = eb.z, a3 = eb.w;
        const float dt = dtc;
        // prefetch step t+1 (independent; hides LDS latency under GEMV)
        eb = embp[ev_s[t + 1]][l];
        dtc = dt_s[t + 1];
        // broadcast h via readlane -> uniform SGPRs (FMA takes SGPR operand directly)
        float s_h[HH];
#pragma unroll
        for (int k = 0; k < HH; k++)
            s_h[k] = __uint_as_float(__builtin_amdgcn_readlane(__float_as_uint(hprev), k));
        // GEMV: 4 independent 32-deep chains (pure register FMAs)
#pragma unroll
        for (int k = 0; k < HH; k++) {
            a0 = fmaf(s_h[k], wk0[k], a0);
            a1 = fmaf(s_h[k], wk1[k], a1);
            a2 = fmaf(s_h[k], wk2[k], a2);
            a3 = fmaf(s_h[k], wk3[k], a3);
        }
        // activations
        float g0 = sig_(a0);                       // i | f
        float g2 = sig_(a2);                       // ib | fb
        float y1 = lo ? a1 + a1 : a1;
        float s1 = sig_(y1);
        float g1 = lo ? fmaf(2.f, s1, -1.f) : s1;  // tanh(z) | sigmoid(o)
        float g3 = softplus_(a3);                  // delta (valid on lo)
        float e  = __expf(-g3 * dt);
        // hi -> lo half swap (VALU permlane, no LDS)
        float f_  = swap_hi_to_lo(g0);
        float o_  = swap_hi_to_lo(g1);
        float fb_ = swap_hi_to_lo(g2);
        // update (all lanes execute; hi lanes produce garbage, never read)
        float cc = fmaf(f_, c_m, g0 * g1);
        float cb = fmaf(fb_, cb_m, g2 * g1);
        float cn = fmaf(cc - cb, e, cb);
        float hn = o_ * tanh_(cn);
        c_m = cn; cb_m = cb;
        if (lo)
            ((float4*)(ccdo_base + (size_t)t * 128))[l] = make_float4(cc, cb, g3, o_);
        hprev = hn;
    }
}

// ---------------- K2: lambda_sample + per-batch integral (grid 256x4, no atomics) ----------------
__global__ __launch_bounds__(256) void k2_sample(const float* __restrict__ dts,
                                                 const float* __restrict__ msk,
                                                 const float* __restrict__ Wl,
                                                 float* ws,
                                                 float* __restrict__ out) {
    __shared__ __align__(16) float sh_s[8][HH];
    __shared__ float redn[8], redd[8];
    const int tid = threadIdx.x;
    const int b = blockIdx.x, q4 = blockIdx.y;
    const int rowg = tid >> 5, lane = tid & 31;
    float4 wl4[8];
#pragma unroll
    for (int q = 0; q < 8; q++) wl4[q] = ((const float4*)(Wl + lane * HH))[q];

    const int base = b * SS + q4 * 256;
    float accn = 0.f, accd = 0.f;

#pragma unroll 2
    for (int it = 0; it < 32; it++) {
        const size_t rr = (size_t)base + it * 8 + rowg;
        float4 v = *(const float4*)(ws + rr * 128 + lane * 4);  // c, cbar, delta, o
        float e_ = __expf(-v.z * dts[rr]);
        float cd = fmaf(v.x - v.y, e_, v.y);
        sh_s[rowg][lane] = v.w * tanh_(cd);   // same-wave write/read, no barrier
        const float4* sh4 = (const float4*)sh_s[rowg];
        float acc = 0.f, acc2 = 0.f;
#pragma unroll
        for (int q = 0; q < 4; q++) {
            float4 s4 = sh4[q];
            acc  = fmaf(s4.x, wl4[q].x, acc);  acc  = fmaf(s4.y, wl4[q].y, acc);
            acc  = fmaf(s4.z, wl4[q].z, acc);  acc  = fmaf(s4.w, wl4[q].w, acc);
        }
#pragma unroll
        for (int q = 4; q < 8; q++) {
            float4 s4 = sh4[q];
            acc2 = fmaf(s4.x, wl4[q].x, acc2); acc2 = fmaf(s4.y, wl4[q].y, acc2);
            acc2 = fmaf(s4.z, wl4[q].z, acc2); acc2 = fmaf(s4.w, wl4[q].w, acc2);
        }
        float sp = softplus_(acc + acc2);
        out[2 + rr * EVN + lane] = sp;
        float ls = sp;
#pragma unroll
        for (int m = 16; m >= 1; m >>= 1) ls += __shfl_xor(ls, m);
        float m_ = msk[rr];
        accn = fmaf(ls, m_, accn);
        accd += m_;
    }
    if (lane == 0) { redn[rowg] = accn; redd[rowg] = accd; }
    __syncthreads();
    if (tid == 0) {
        float n = 0.f, d = 0.f;
#pragma unroll
        for (int g = 0; g < 8; g++) { n += redn[g]; d += redd[g]; }
        ws[NUM0 + q4 * 256 + b] = n;
        ws[DEN0 + q4 * 256 + b] = d;
    }
}

// ---------------- K3: log-lambda at target (recomputes h from ccdo) ----------------
__global__ __launch_bounds__(256) void k3_loglam(const int* __restrict__ event,
                                                 const float* __restrict__ dtime,
                                                 const float* __restrict__ Wl,
                                                 float* ws) {
    __shared__ float wl_s[EVN * HH];
    __shared__ float redl[8], redc[8];
    const int tid = threadIdx.x;
    const int b = blockIdx.x, q4 = blockIdx.y;
    for (int idx = tid; idx < EVN * HH; idx += 256) wl_s[idx] = Wl[idx];
    const int rowg = tid >> 5, lane = tid & 31;
    const int t_end = (q4 < 3) ? (q4 + 1) * 256 : TP1;
    float accl = 0.f, accc = 0.f;
    __syncthreads();

    for (int t = q4 * 256 + rowg; t < t_end; t += 8) {
        int tgt = event[b * T2C + t + 1];
        if (tgt < EVN) {
            float4 v = *(const float4*)(ws + ((size_t)b * TP1 + t) * 128 + lane * 4);
            float dt = dtime[b * T2C + t + 1];
            float e_ = __expf(-v.z * dt);
            float cd = fmaf(v.x - v.y, e_, v.y);
            float h = v.w * tanh_(cd);
            float p = h * wl_s[tgt * HH + lane];
#pragma unroll
            for (int m = 16; m >= 1; m >>= 1) p += __shfl_xor(p, m);
            accl += __logf(softplus_(p) + EPSF);
            accc += 1.f;
        }
    }
    if (lane == 0) { redl[rowg] = accl; redc[rowg] = accc; }
    __syncthreads();
    if (tid == 0) {
        float l = 0.f, c = 0.f;
#pragma unroll
        for (int g = 0; g < 8; g++) { l += redl[g]; c += redc[g]; }
        ws[LL0 + q4 * 256 + b] = l;
        ws[NEV0 + q4 * 256 + b] = c;
    }
}

// ---------------- K4: final reduction ----------------
__global__ __launch_bounds__(256) void k4_final(const float* __restrict__ duration,
                                                float* ws,
                                                float* __restrict__ out) {
    __shared__ float r1[256], r2[256];
    int tid = threadIdx.x;
    float nmr = 0.f, den = 0.f, llb = 0.f, nev = 0.f;
#pragma unroll
    for (int q = 0; q < 4; q++) {
        nmr += ws[NUM0 + q * 256 + tid];
        den += ws[DEN0 + q * 256 + tid];
        llb += ws[LL0 + q * 256 + tid];
        nev += ws[NEV0 + q * 256 + tid];
    }
    r1[tid] = (nmr / den) * duration[tid] - llb;
    r2[tid] = nev;
    __syncthreads();
    for (int ofs = 128; ofs > 0; ofs >>= 1) {
        if (tid < ofs) { r1[tid] += r1[tid + ofs]; r2[tid] += r2[tid + ofs]; }
        __syncthreads();
    }
    if (tid == 0) { out[0] = r1[0]; out[1] = r2[0]; }
}

extern "C" void kernel_launch(void* const* d_in, const int* in_sizes, int n_in,
                              void* d_out, int out_size, void* d_ws, size_t ws_size,
                              hipStream_t stream) {
    const int*   event    = (const int*)d_in[0];
    const float* dtime    = (const float*)d_in[1];
    const float* duration = (const float*)d_in[2];
    const float* dts      = (const float*)d_in[3];
    // d_in[4] index_of_hidden_sampling: dead in reference
    const float* msk      = (const float*)d_in[5];
    const float* Emb      = (const float*)d_in[6];
    const float* W        = (const float*)d_in[7];
    const float* bias     = (const float*)d_in[8];
    const float* Wl       = (const float*)d_in[9];
    float* out = (float*)d_out;
    float* ws  = (float*)d_ws;

    k0_embw<<<1, 256, 0, stream>>>(Emb, W, bias, ws);
    k1_recur<<<BB, 64, 0, stream>>>(event, dtime, ws);
    k2_sample<<<dim3(BB, 4), 256, 0, stream>>>(dts, msk, Wl, ws, out);
    k3_loglam<<<dim3(BB, 4), 256, 0, stream>>>(event, dtime, Wl, ws);
    k4_final<<<1, 256, 0, stream>>>(duration, ws, out);
}